// Round 8
// baseline (983.486 us; speedup 1.0000x reference)
//
#include <hip/hip_runtime.h>

#define WG 256

#define MLP_FMA16(ACC, A, W) do { \
    ACC[0][0]=fmaf(A.x,W.x,ACC[0][0]); ACC[0][1]=fmaf(A.x,W.y,ACC[0][1]); \
    ACC[0][2]=fmaf(A.x,W.z,ACC[0][2]); ACC[0][3]=fmaf(A.x,W.w,ACC[0][3]); \
    ACC[1][0]=fmaf(A.y,W.x,ACC[1][0]); ACC[1][1]=fmaf(A.y,W.y,ACC[1][1]); \
    ACC[1][2]=fmaf(A.y,W.z,ACC[1][2]); ACC[1][3]=fmaf(A.y,W.w,ACC[1][3]); \
    ACC[2][0]=fmaf(A.z,W.x,ACC[2][0]); ACC[2][1]=fmaf(A.z,W.y,ACC[2][1]); \
    ACC[2][2]=fmaf(A.z,W.z,ACC[2][2]); ACC[2][3]=fmaf(A.z,W.w,ACC[2][3]); \
    ACC[3][0]=fmaf(A.w,W.x,ACC[3][0]); ACC[3][1]=fmaf(A.w,W.y,ACC[3][1]); \
    ACC[3][2]=fmaf(A.w,W.z,ACC[3][2]); ACC[3][3]=fmaf(A.w,W.w,ACC[3][3]); \
} while (0)

// ---------------- XCD-partitioned slot fill (block role) -------------------
// R2: 8-way XCD partition keeps cur[] atomic lines XCD-local (un-partitioned
// atomics cost ~175us). R8: dense int4 co-load of s alongside r (proven in
// R2's scan): removes the scattered DEPENDENT s[e] load from the hit path
// (each s line was being fetched by all 8 XCD replicas, randomly). Non-hit
// s words are L3-streamed -- cheap. R3: gather stays standalone. R4: LDS
// weight staging. R5: 64-row/4x4 tile. R6: float4 gather. R7: interleave
// null -> fill is throughput-bound, fill-first layout kept.
__device__ __forceinline__ void fill_role(int xcd, int w,
    const int* __restrict__ s, const int* __restrict__ r,
    int* __restrict__ cur, int* __restrict__ sl,
    int cap, int E, int n, int W)
{
    const int lo = (int)(((long)n * xcd) >> 3);
    const int hi = (int)(((long)n * (xcd + 1)) >> 3);
    int chunk = (E + W - 1) / W;
    chunk = (chunk + 3) & ~3;                      // int4 alignment
    const int e0 = w * chunk;
    const int e1 = min(E, e0 + chunk);

    auto fill1 = [&](int v, int sv) {
        if (v >= lo && v < hi) {
            const int p = atomicAdd(&cur[v], 1);
            if (p < cap) sl[(size_t)v * cap + p] = sv;
        }
    };

    for (int e = e0 + (int)threadIdx.x * 4; e < e1; e += WG * 4) {
        if (e + 4 <= e1) {
            const int4 rv = *(const int4*)&r[e];
            const int4 sv = *(const int4*)&s[e];
            fill1(rv.x, sv.x);
            fill1(rv.y, sv.y);
            fill1(rv.z, sv.z);
            fill1(rv.w, sv.w);
        } else {
            for (int j = 0; e + j < e1; ++j) fill1(r[e + j], s[e + j]);
        }
    }
}

// fills that ride along inside an MLP dispatch (up to 2 graphs)
struct FillPair {
    const int* s0; const int* r0; int* cur0; int* sl0; int cap0, E0, n0, W0;
    const int* s1; const int* r1; int* cur1; int* sl1; int cap1, E1, n1, W1;
    int FILLB;                                     // = 8*(W0+W1); 0 = no fill
};

// =============== fused: node-MLP (+out1) then msg-MLP of next layer =========
// R1 champion structure: 64-row blocks, 256 thr, 4x4 acc, LDS weights,
// sXT capped at 64 rows (concat input as two K-phases). ~34.8 KB -> 4 blk/CU.
template<int DINA, bool HAS_B, bool HAS_SKIP, bool GATHER_A,
         int MSG_DOUT, bool PARTIAL_MSG, bool WRITE_OUT1>
__global__ __launch_bounds__(WG)
void mlp2_fused(const float* __restrict__ inA, const int* __restrict__ gidxA,
                const float* __restrict__ inB,
                const float* __restrict__ W1, const float* __restrict__ b1,
                const float* __restrict__ W2, const float* __restrict__ b2,
                const float* __restrict__ skip, float* __restrict__ out1,
                const float* __restrict__ M1, const float* __restrict__ mb1,
                const float* __restrict__ M2, const float* __restrict__ mb2,
                float* __restrict__ outM, int msgN, int n, FillPair fa)
{
    if (fa.FILLB > 0 && (int)blockIdx.x < fa.FILLB) {
        const int xcd = blockIdx.x & 7;
        const int w = blockIdx.x >> 3;
        if (w < fa.W0)
            fill_role(xcd, w, fa.s0, fa.r0, fa.cur0, fa.sl0, fa.cap0, fa.E0, fa.n0, fa.W0);
        else
            fill_role(xcd, w - fa.W0, fa.s1, fa.r1, fa.cur1, fa.sl1, fa.cap1, fa.E1, fa.n1, fa.W1);
        return;
    }
    const int bid = blockIdx.x - fa.FILLB;

    constexpr int XP = 68;                           // b128-aligned, conflict-free
    __shared__ __align__(16) float sXT[64][XP];      // X^T phases / H^T / O^T / H2^T
    __shared__ __align__(16) float sW[64 * 64];      // W1 phases / W2 / M1 / M2
    __shared__ float sb[128];
    __shared__ float sW2d[128];                      // decode W2 (64x2)
    __shared__ float sb2d[2];

    const int tid = threadIdx.x;
    const int tx = tid & 15, ty = tid >> 4;
    const int c0 = tx * 4, r0 = ty * 4;
    const int row0 = bid * 64;
    const int lrow = tid & 63;
    const int kq0 = (tid >> 6) * 4;

    // ---- stage W1 phase A (DINA rows), biases
    for (int i = tid * 4; i < DINA * 64; i += WG * 4)
        *(float4*)&sW[i] = *(const float4*)&W1[i];
    if (tid < 64) sb[tid] = b1[tid];
    else if (tid < 128) sb[tid] = b2[tid - 64];

    // ---- stage X^T phase A (lane = row, conflict-free)
    {
        const int rg = min(row0 + lrow, n - 1);
        const int ra = GATHER_A ? gidxA[rg] : rg;
        const float* pA = inA + (size_t)ra * DINA;
        #pragma unroll
        for (int kq = kq0; kq < DINA; kq += 16) {
            const float4 v = *(const float4*)(pA + kq);
            sXT[kq + 0][lrow] = v.x; sXT[kq + 1][lrow] = v.y;
            sXT[kq + 2][lrow] = v.z; sXT[kq + 3][lrow] = v.w;
        }
    }
    __syncthreads();

    // ---- GEMM1 phase A
    float acc[4][4] = {};
    #pragma unroll 8
    for (int k = 0; k < DINA; ++k) {
        const float4 a = *(const float4*)&sXT[k][r0];
        const float4 w = *(const float4*)&sW[k * 64 + c0];
        MLP_FMA16(acc, a, w);
    }

    // ---- GEMM1 phase B: inB against W1 rows DINA..DINA+63
    if constexpr (HAS_B) {
        __syncthreads();
        for (int i = tid * 4; i < 64 * 64; i += WG * 4)
            *(float4*)&sW[i] = *(const float4*)&W1[DINA * 64 + i];
        {
            const int rg = min(row0 + lrow, n - 1);
            const float* pB = inB + (size_t)rg * 64;
            #pragma unroll
            for (int kq = kq0; kq < 64; kq += 16) {
                const float4 v = *(const float4*)(pB + kq);
                sXT[kq + 0][lrow] = v.x; sXT[kq + 1][lrow] = v.y;
                sXT[kq + 2][lrow] = v.z; sXT[kq + 3][lrow] = v.w;
            }
        }
        __syncthreads();
        #pragma unroll 8
        for (int k = 0; k < 64; ++k) {
            const float4 a = *(const float4*)&sXT[k][r0];
            const float4 w = *(const float4*)&sW[k * 64 + c0];
            MLP_FMA16(acc, a, w);
        }
    }
    __syncthreads();

    // ---- stage W2; write H^T
    for (int i = tid * 4; i < 64 * 64; i += WG * 4)
        *(float4*)&sW[i] = *(const float4*)&W2[i];
    #pragma unroll
    for (int j = 0; j < 4; ++j) {
        const float bj = sb[c0 + j];
        *(float4*)&sXT[c0 + j][r0] = make_float4(
            fmaxf(acc[0][j] + bj, 0.f), fmaxf(acc[1][j] + bj, 0.f),
            fmaxf(acc[2][j] + bj, 0.f), fmaxf(acc[3][j] + bj, 0.f));
    }
    __syncthreads();

    // ---- GEMM2
    float acc2[4][4] = {};
    #pragma unroll 8
    for (int k = 0; k < 64; ++k) {
        const float4 a = *(const float4*)&sXT[k][r0];
        const float4 w = *(const float4*)&sW[k * 64 + c0];
        MLP_FMA16(acc2, a, w);
    }

    // ---- O = acc2 + b2 (+skip); write out1
    float ofull[4][4];
    #pragma unroll
    for (int i = 0; i < 4; ++i) {
        const int row = row0 + r0 + i;
        float4 s = make_float4(0.f, 0.f, 0.f, 0.f);
        if (HAS_SKIP && row < n) s = *(const float4*)&skip[(size_t)row * 64 + c0];
        ofull[i][0] = acc2[i][0] + sb[64 + c0 + 0] + s.x;
        ofull[i][1] = acc2[i][1] + sb[64 + c0 + 1] + s.y;
        ofull[i][2] = acc2[i][2] + sb[64 + c0 + 2] + s.z;
        ofull[i][3] = acc2[i][3] + sb[64 + c0 + 3] + s.w;
        if (WRITE_OUT1 && row < n)
            *(float4*)&out1[(size_t)row * 64 + c0] =
                make_float4(ofull[i][0], ofull[i][1], ofull[i][2], ofull[i][3]);
    }

    // ================= msg tail =================
    if constexpr (MSG_DOUT > 0) {
        if (!PARTIAL_MSG || row0 < msgN) {   // block-uniform
            __syncthreads();
            for (int i = tid * 4; i < 64 * 64; i += WG * 4)
                *(float4*)&sW[i] = *(const float4*)&M1[i];
            if constexpr (MSG_DOUT == 64) {
                if (tid < 64) sb[tid] = mb1[tid];
                else if (tid < 128) sb[tid] = mb2[tid - 64];
            } else {
                if (tid < 64) sb[tid] = mb1[tid];
                else if (tid < 192) sW2d[tid - 64] = M2[tid - 64];
                else if (tid < 194) sb2d[tid - 192] = mb2[tid - 192];
            }
            #pragma unroll
            for (int j = 0; j < 4; ++j)
                *(float4*)&sXT[c0 + j][r0] =
                    make_float4(ofull[0][j], ofull[1][j], ofull[2][j], ofull[3][j]);
            __syncthreads();

            // GEMM3: H2 = relu(O @ M1 + mb1)
            float acc3[4][4] = {};
            #pragma unroll 8
            for (int k = 0; k < 64; ++k) {
                const float4 a = *(const float4*)&sXT[k][r0];
                const float4 w = *(const float4*)&sW[k * 64 + c0];
                MLP_FMA16(acc3, a, w);
            }
            __syncthreads();
            if constexpr (MSG_DOUT == 64) {
                for (int i = tid * 4; i < 64 * 64; i += WG * 4)
                    *(float4*)&sW[i] = *(const float4*)&M2[i];
            }
            #pragma unroll
            for (int j = 0; j < 4; ++j) {
                const float bj = sb[c0 + j];
                *(float4*)&sXT[c0 + j][r0] = make_float4(
                    fmaxf(acc3[0][j] + bj, 0.f), fmaxf(acc3[1][j] + bj, 0.f),
                    fmaxf(acc3[2][j] + bj, 0.f), fmaxf(acc3[3][j] + bj, 0.f));
            }
            __syncthreads();

            if constexpr (MSG_DOUT == 64) {
                float accM[4][4] = {};
                #pragma unroll 8
                for (int k = 0; k < 64; ++k) {
                    const float4 a = *(const float4*)&sXT[k][r0];
                    const float4 w = *(const float4*)&sW[k * 64 + c0];
                    MLP_FMA16(accM, a, w);
                }
                #pragma unroll
                for (int i = 0; i < 4; ++i) {
                    const int row = row0 + r0 + i;
                    if (row < msgN)
                        *(float4*)&outM[(size_t)row * 64 + c0] =
                            make_float4(accM[i][0] + sb[64 + c0 + 0],
                                        accM[i][1] + sb[64 + c0 + 1],
                                        accM[i][2] + sb[64 + c0 + 2],
                                        accM[i][3] + sb[64 + c0 + 3]);
                }
            } else {
                // decode: 128 threads: (row,col)=(tid>>1, tid&1)
                if (tid < 128) {
                    const int lr = tid >> 1, col = tid & 1;
                    float o0 = sb2d[col], o1 = 0.0f;
                    #pragma unroll 8
                    for (int k = 0; k < 64; k += 2) {
                        o0 = fmaf(sXT[k][lr],     sW2d[k * 2 + col],       o0);
                        o1 = fmaf(sXT[k + 1][lr], sW2d[(k + 1) * 2 + col], o1);
                    }
                    const int row = row0 + lr;
                    if (row < msgN) outM[(size_t)row * 2 + col] = o0 + o1;
                }
            }
        }
    }
}

// plain node-only MLP, R1 structure
template<int DINA, bool HAS_B, bool HAS_SKIP, bool GATHER_A>
__global__ __launch_bounds__(WG)
void mlp2_rt(const float* __restrict__ inA, const int* __restrict__ gidxA,
             const float* __restrict__ inB,
             const float* __restrict__ W1, const float* __restrict__ b1,
             const float* __restrict__ W2, const float* __restrict__ b2,
             const float* __restrict__ skip,
             float* __restrict__ out, int n)
{
    constexpr int XP = 68;
    __shared__ __align__(16) float sXT[64][XP];
    __shared__ __align__(16) float sW[64 * 64];
    __shared__ float sb[128];

    const int tid = threadIdx.x;
    const int tx = tid & 15, ty = tid >> 4;
    const int c0 = tx * 4, r0 = ty * 4;
    const int row0 = blockIdx.x * 64;
    const int lrow = tid & 63;
    const int kq0 = (tid >> 6) * 4;

    for (int i = tid * 4; i < DINA * 64; i += WG * 4)
        *(float4*)&sW[i] = *(const float4*)&W1[i];
    if (tid < 64) sb[tid] = b1[tid];
    else if (tid < 128) sb[tid] = b2[tid - 64];

    {
        const int rg = min(row0 + lrow, n - 1);
        const int ra = GATHER_A ? gidxA[rg] : rg;
        const float* pA = inA + (size_t)ra * DINA;
        #pragma unroll
        for (int kq = kq0; kq < DINA; kq += 16) {
            const float4 v = *(const float4*)(pA + kq);
            sXT[kq + 0][lrow] = v.x; sXT[kq + 1][lrow] = v.y;
            sXT[kq + 2][lrow] = v.z; sXT[kq + 3][lrow] = v.w;
        }
    }
    __syncthreads();

    float acc[4][4] = {};
    #pragma unroll 8
    for (int k = 0; k < DINA; ++k) {
        const float4 a = *(const float4*)&sXT[k][r0];
        const float4 w = *(const float4*)&sW[k * 64 + c0];
        MLP_FMA16(acc, a, w);
    }
    if constexpr (HAS_B) {
        __syncthreads();
        for (int i = tid * 4; i < 64 * 64; i += WG * 4)
            *(float4*)&sW[i] = *(const float4*)&W1[DINA * 64 + i];
        {
            const int rg = min(row0 + lrow, n - 1);
            const float* pB = inB + (size_t)rg * 64;
            #pragma unroll
            for (int kq = kq0; kq < 64; kq += 16) {
                const float4 v = *(const float4*)(pB + kq);
                sXT[kq + 0][lrow] = v.x; sXT[kq + 1][lrow] = v.y;
                sXT[kq + 2][lrow] = v.z; sXT[kq + 3][lrow] = v.w;
            }
        }
        __syncthreads();
        #pragma unroll 8
        for (int k = 0; k < 64; ++k) {
            const float4 a = *(const float4*)&sXT[k][r0];
            const float4 w = *(const float4*)&sW[k * 64 + c0];
            MLP_FMA16(acc, a, w);
        }
    }
    __syncthreads();

    for (int i = tid * 4; i < 64 * 64; i += WG * 4)
        *(float4*)&sW[i] = *(const float4*)&W2[i];
    #pragma unroll
    for (int j = 0; j < 4; ++j) {
        const float bj = sb[c0 + j];
        *(float4*)&sXT[c0 + j][r0] = make_float4(
            fmaxf(acc[0][j] + bj, 0.f), fmaxf(acc[1][j] + bj, 0.f),
            fmaxf(acc[2][j] + bj, 0.f), fmaxf(acc[3][j] + bj, 0.f));
    }
    __syncthreads();

    float acc2[4][4] = {};
    #pragma unroll 8
    for (int k = 0; k < 64; ++k) {
        const float4 a = *(const float4*)&sXT[k][r0];
        const float4 w = *(const float4*)&sW[k * 64 + c0];
        MLP_FMA16(acc2, a, w);
    }
    #pragma unroll
    for (int i = 0; i < 4; ++i) {
        const int row = row0 + r0 + i;
        if (row < n) {
            float4 o = make_float4(acc2[i][0] + sb[64 + c0 + 0],
                                   acc2[i][1] + sb[64 + c0 + 1],
                                   acc2[i][2] + sb[64 + c0 + 2],
                                   acc2[i][3] + sb[64 + c0 + 3]);
            if (HAS_SKIP) {
                const float4 s = *(const float4*)&skip[(size_t)row * 64 + c0];
                o.x += s.x; o.y += s.y; o.z += s.z; o.w += s.w;
            }
            *(float4*)&out[(size_t)row * 64 + c0] = o;
        }
    }
}

// ===== dispatch 1: fine-graph fill UNION encode+msg0 MLP (R6 layout) ========
__global__ __launch_bounds__(WG)
void fill_enc_k(const int* __restrict__ s0, const int* __restrict__ r0v,
                int* cu0, int* sl0, int cap0, int E0, int n0, int W0, int FILLB,
                const float* __restrict__ x,
                const float* __restrict__ We1, const float* __restrict__ be1,
                const float* __restrict__ We2, const float* __restrict__ be2,
                float* __restrict__ h0,
                const float* __restrict__ M1, const float* __restrict__ mb1,
                const float* __restrict__ M2, const float* __restrict__ mb2,
                float* __restrict__ msg0, int N)
{
    constexpr int XP = 68;
    __shared__ __align__(16) float sXT[64][XP];
    __shared__ float sb[128];

    if ((int)blockIdx.x < FILLB) {
        fill_role(blockIdx.x & 7, blockIdx.x >> 3, s0, r0v, cu0, sl0, cap0, E0, n0, W0);
        return;
    }

    // ---------------- encode role: h0 = MLP2(x); msg0 = MLP2(h0) ----------------
    const int bid = blockIdx.x - FILLB;
    const int tid = threadIdx.x;
    const int tx = tid & 15, ty = tid >> 4;
    const int c0 = tx * 4, r0 = ty * 4;
    const int row0 = bid * 64;
    const int lrow = tid & 63;
    const int kq0 = (tid >> 6) * 4;

    if (tid < 64) sb[tid] = be1[tid];
    else if (tid < 128) sb[tid] = be2[tid - 64];

    {
        const int rg = min(row0 + lrow, N - 1);
        const float* pA = x + (size_t)rg * 16;
        const float4 v = *(const float4*)(pA + kq0);
        sXT[kq0 + 0][lrow] = v.x; sXT[kq0 + 1][lrow] = v.y;
        sXT[kq0 + 2][lrow] = v.z; sXT[kq0 + 3][lrow] = v.w;
    }
    __syncthreads();

    float acc[4][4] = {};
    #pragma unroll
    for (int k = 0; k < 16; ++k) {
        const float4 a = *(const float4*)&sXT[k][r0];
        const float4 w = *(const float4*)&We1[k * 64 + c0];
        MLP_FMA16(acc, a, w);
    }
    __syncthreads();
    #pragma unroll
    for (int j = 0; j < 4; ++j) {
        const float bj = sb[c0 + j];
        *(float4*)&sXT[c0 + j][r0] = make_float4(
            fmaxf(acc[0][j] + bj, 0.f), fmaxf(acc[1][j] + bj, 0.f),
            fmaxf(acc[2][j] + bj, 0.f), fmaxf(acc[3][j] + bj, 0.f));
    }
    __syncthreads();

    float acc2[4][4] = {};
    #pragma unroll 8
    for (int k = 0; k < 64; ++k) {
        const float4 a = *(const float4*)&sXT[k][r0];
        const float4 w = *(const float4*)&We2[k * 64 + c0];
        MLP_FMA16(acc2, a, w);
    }
    float ofull[4][4];
    #pragma unroll
    for (int i = 0; i < 4; ++i) {
        const int row = row0 + r0 + i;
        ofull[i][0] = acc2[i][0] + sb[64 + c0 + 0];
        ofull[i][1] = acc2[i][1] + sb[64 + c0 + 1];
        ofull[i][2] = acc2[i][2] + sb[64 + c0 + 2];
        ofull[i][3] = acc2[i][3] + sb[64 + c0 + 3];
        if (row < N)
            *(float4*)&h0[(size_t)row * 64 + c0] =
                make_float4(ofull[i][0], ofull[i][1], ofull[i][2], ofull[i][3]);
    }

    __syncthreads();
    if (tid < 64) sb[tid] = mb1[tid];
    else if (tid < 128) sb[tid] = mb2[tid - 64];
    #pragma unroll
    for (int j = 0; j < 4; ++j)
        *(float4*)&sXT[c0 + j][r0] =
            make_float4(ofull[0][j], ofull[1][j], ofull[2][j], ofull[3][j]);
    __syncthreads();

    float acc3[4][4] = {};
    #pragma unroll 8
    for (int k = 0; k < 64; ++k) {
        const float4 a = *(const float4*)&sXT[k][r0];
        const float4 w = *(const float4*)&M1[k * 64 + c0];
        MLP_FMA16(acc3, a, w);
    }
    __syncthreads();
    #pragma unroll
    for (int j = 0; j < 4; ++j) {
        const float bj = sb[c0 + j];
        *(float4*)&sXT[c0 + j][r0] = make_float4(
            fmaxf(acc3[0][j] + bj, 0.f), fmaxf(acc3[1][j] + bj, 0.f),
            fmaxf(acc3[2][j] + bj, 0.f), fmaxf(acc3[3][j] + bj, 0.f));
    }
    __syncthreads();

    float accM[4][4] = {};
    #pragma unroll 8
    for (int k = 0; k < 64; ++k) {
        const float4 a = *(const float4*)&sXT[k][r0];
        const float4 w = *(const float4*)&M2[k * 64 + c0];
        MLP_FMA16(accM, a, w);
    }
    #pragma unroll
    for (int i = 0; i < 4; ++i) {
        const int row = row0 + r0 + i;
        if (row < N)
            *(float4*)&msg0[(size_t)row * 64 + c0] =
                make_float4(accM[i][0] + sb[64 + c0 + 0],
                            accM[i][1] + sb[64 + c0 + 1],
                            accM[i][2] + sb[64 + c0 + 2],
                            accM[i][3] + sb[64 + c0 + 3]);
    }
}

// ---------------- slot gather-sum: float4 rows, 4 rows/wave-instr (R6) -----
template<bool REMAP>
__global__ __launch_bounds__(WG)
void gather_slots_k(const int* __restrict__ deg, const int* __restrict__ slots,
                    int cap, const int* __restrict__ remap,
                    const float* __restrict__ tab, float* __restrict__ aggr, int n)
{
    const int node = blockIdx.x * (WG / 64) + (threadIdx.x >> 6);
    const int lane = threadIdx.x & 63;
    if (node >= n) return;
    const int d = min(deg[node], cap);
    const int* sl = slots + (size_t)node * cap;

    int myidx = 0;
    if (lane < d) {
        myidx = sl[lane];
        if (REMAP) myidx = remap[myidx];
    }

    const int g  = lane >> 4;          // row-group 0..3
    const int c4 = (lane & 15) * 4;    // column quad

    float4 a0 = make_float4(0.f, 0.f, 0.f, 0.f);
    float4 a1 = make_float4(0.f, 0.f, 0.f, 0.f);
    float4 a2 = make_float4(0.f, 0.f, 0.f, 0.f);
    float4 a3 = make_float4(0.f, 0.f, 0.f, 0.f);

    int j = 0;
    for (; j + 16 <= d; j += 16) {
        const int t0 = __shfl(myidx, j + g);
        const int t1 = __shfl(myidx, j + 4 + g);
        const int t2 = __shfl(myidx, j + 8 + g);
        const int t3 = __shfl(myidx, j + 12 + g);
        const float4 v0 = *(const float4*)&tab[(size_t)t0 * 64 + c4];
        const float4 v1 = *(const float4*)&tab[(size_t)t1 * 64 + c4];
        const float4 v2 = *(const float4*)&tab[(size_t)t2 * 64 + c4];
        const float4 v3 = *(const float4*)&tab[(size_t)t3 * 64 + c4];
        a0.x += v0.x; a0.y += v0.y; a0.z += v0.z; a0.w += v0.w;
        a1.x += v1.x; a1.y += v1.y; a1.z += v1.z; a1.w += v1.w;
        a2.x += v2.x; a2.y += v2.y; a2.z += v2.z; a2.w += v2.w;
        a3.x += v3.x; a3.y += v3.y; a3.z += v3.z; a3.w += v3.w;
    }
    for (; j < d; j += 4) {
        const int jj = j + g;
        const int t = __shfl(myidx, jj < 63 ? jj : 0);   // uniform shfl
        if (jj < d) {
            const float4 v = *(const float4*)&tab[(size_t)t * 64 + c4];
            a0.x += v.x; a0.y += v.y; a0.z += v.z; a0.w += v.w;
        }
    }

    // combine accumulators, then reduce across the 4 row-groups
    a0.x += a1.x + a2.x + a3.x;
    a0.y += a1.y + a2.y + a3.y;
    a0.z += a1.z + a2.z + a3.z;
    a0.w += a1.w + a2.w + a3.w;

    a0.x += __shfl_xor(a0.x, 16); a0.y += __shfl_xor(a0.y, 16);
    a0.z += __shfl_xor(a0.z, 16); a0.w += __shfl_xor(a0.w, 16);
    a0.x += __shfl_xor(a0.x, 32); a0.y += __shfl_xor(a0.y, 32);
    a0.z += __shfl_xor(a0.z, 32); a0.w += __shfl_xor(a0.w, 32);

    if (lane < 16)
        *(float4*)&aggr[(size_t)node * 64 + c4] = a0;
}

extern "C" void kernel_launch(void* const* d_in, const int* in_sizes, int n_in,
                              void* d_out, int out_size, void* d_ws, size_t ws_size,
                              hipStream_t stream)
{
    const float* x    = (const float*)d_in[0];
    const float* We1  = (const float*)d_in[1];
    const float* be1  = (const float*)d_in[2];
    const float* We2  = (const float*)d_in[3];
    const float* be2  = (const float*)d_in[4];
    const float* Wm1  = (const float*)d_in[5];
    const float* bm1  = (const float*)d_in[6];
    const float* Wm2  = (const float*)d_in[7];
    const float* bm2  = (const float*)d_in[8];
    const float* Wn1  = (const float*)d_in[9];
    const float* bn1  = (const float*)d_in[10];
    const float* Wn2  = (const float*)d_in[11];
    const float* bn2  = (const float*)d_in[12];
    const float* Wd1  = (const float*)d_in[13];
    const float* bd1  = (const float*)d_in[14];
    const float* Wd2  = (const float*)d_in[15];
    const float* bd2  = (const float*)d_in[16];
    const int* s_fine = (const int*)d_in[17];
    const int* r_fine = (const int*)d_in[18];
    const int* s_ds   = (const int*)d_in[19];
    const int* r_ds   = (const int*)d_in[20];
    const int* s_p    = (const int*)d_in[21];
    const int* r_p    = (const int*)d_in[22];
    const int* s_us   = (const int*)d_in[23];
    const int* r_us   = (const int*)d_in[24];
    const int* uppool   = (const int*)d_in[25];
    const int* downpool = (const int*)d_in[26];

    const int N   = in_sizes[0] / 16;
    const int E   = in_sizes[17];
    const int EDS = in_sizes[19];
    const int EP  = in_sizes[21];
    const int EUS = in_sizes[23];
    const int NP  = in_sizes[26];

    const int CAP_FINE = 48, CAP_DS = 32, CAP_PP = 48, CAP_US = 32;

    // ---- workspace ----
    float* B0  = (float*)d_ws;
    float* B1  = B0 + (size_t)N * 64;
    float* B2  = B1 + (size_t)N * 64;
    float* B3  = B2 + (size_t)N * 64;
    float* HPa = B3 + (size_t)N * 64;
    float* HPb = HPa + (size_t)NP * 64;
    int* ip = (int*)(HPb + (size_t)NP * 64);
    auto alloc_i = [&](size_t n) { int* p = ip; ip += n; return p; };
    int* cur_fine = alloc_i(N);
    int* cur_ds   = alloc_i(N);
    int* cur_pp   = alloc_i(NP);
    int* cur_us   = alloc_i(NP);
    int* sl_fine  = alloc_i((size_t)N * CAP_FINE);
    int* sl_ds    = alloc_i((size_t)N * CAP_DS);
    int* sl_pp    = alloc_i((size_t)NP * CAP_PP);
    int* sl_us    = alloc_i((size_t)NP * CAP_US);

    const int gN  = (N + 63) / 64;
    const int gNP = (NP + 63) / 64;
    const int gaN  = (N + 3) / 4;
    const int gaNP = (NP + 3) / 4;

    const FillPair fnone = {};

    // ---- fine fill + encode in one dispatch (ds/pp/us fills deferred)
    hipMemsetAsync(cur_fine, 0, (size_t)(2 * N + 2 * NP) * sizeof(int), stream);
    {
        const int W_FINE = 256;
        const int FILLB = 8 * W_FINE;   // 2048
        fill_enc_k<<<FILLB + gN, WG, 0, stream>>>(
            s_fine, r_fine, cur_fine, sl_fine, CAP_FINE, E, N, W_FINE, FILLB,
            x, We1, be1, We2, be2, B0,
            Wm1 + 0*4096, bm1 + 0*64, Wm2 + 0*4096, bm2 + 0*64, B1, N);
    }
    gather_slots_k<false><<<gaN,WG,0,stream>>>(cur_fine,sl_fine,CAP_FINE,nullptr,B1,B2,N);

    // ---- F_n0m1: node0(h0,B2) -> h1=B3 ; msg1=B0  [+ ds fill riding along]
    {
        const int W_DS = 128;
        FillPair fds = { s_ds, r_ds, cur_ds, sl_ds, CAP_DS, EDS, N, W_DS,
                         nullptr, nullptr, nullptr, nullptr, 0, 0, 0, 0,
                         8 * W_DS };
        mlp2_fused<64,true,false,false,64,false,true><<<8*128 + gN,WG,0,stream>>>(
            B0,nullptr,B2, Wn1+0*8192,bn1+0*64,Wn2+0*4096,bn2+0*64, nullptr,B3,
            Wm1+1*4096,bm1+1*64,Wm2+1*4096,bm2+1*64, B0, N, N, fds);
    }
    gather_slots_k<false><<<gaN,WG,0,stream>>>(cur_fine,sl_fine,CAP_FINE,nullptr,B0,B2,N);

    // ---- F_n1m2: node1(h1,B2) -> h2=B1 (skip) ; msg2=B0 rows<NP  [+ pp & us fills]
    {
        const int W_PP = 64, W_US = 32;
        FillPair fpu = { s_p,  r_p,  cur_pp, sl_pp, CAP_PP, EP,  NP, W_PP,
                         s_us, r_us, cur_us, sl_us, CAP_US, EUS, NP, W_US,
                         8 * (W_PP + W_US) };
        mlp2_fused<64,true,false,false,64,true,true><<<8*(64+32) + gN,WG,0,stream>>>(
            B3,nullptr,B2, Wn1+1*8192,bn1+1*64,Wn2+1*4096,bn2+1*64, nullptr,B1,
            Wm1+2*4096,bm1+2*64,Wm2+2*4096,bm2+2*64, B0, NP, N, fpu);
    }
    gather_slots_k<true><<<gaN,WG,0,stream>>>(cur_ds,sl_ds,CAP_DS,uppool,B0,B2,N);

    // ---- N2: node2 (h2[uppool], B2) -> g=B3
    mlp2_rt<64,true,false,true><<<gN,WG,0,stream>>>(
        B1,uppool,B2, Wn1+2*8192,bn1+2*64,Wn2+2*4096,bn2+2*64, nullptr,B3,N);

    // ---- M3: msg3 over g[downpool] -> HPa
    mlp2_rt<64,false,false,true><<<gNP,WG,0,stream>>>(
        B3,downpool,nullptr, Wm1+3*4096,bm1+3*64,Wm2+3*4096,bm2+3*64, nullptr,HPa,NP);
    gather_slots_k<false><<<gaNP,WG,0,stream>>>(cur_pp,sl_pp,CAP_PP,nullptr,HPa,B2,NP);

    // ---- F_n3m4: node3(g[downpool],B2) -> hp1=HPb ; msg4=HPa
    mlp2_fused<64,true,false,true,64,false,true><<<gNP,WG,0,stream>>>(
        B3,downpool,B2, Wn1+3*8192,bn1+3*64,Wn2+3*4096,bn2+3*64, nullptr,HPb,
        Wm1+4*4096,bm1+4*64,Wm2+4*4096,bm2+4*64, HPa, NP, NP, fnone);
    gather_slots_k<false><<<gaNP,WG,0,stream>>>(cur_pp,sl_pp,CAP_PP,nullptr,HPa,B2,NP);

    // ---- F_n4m5: node4(hp1,B2) -> hp2=HPa ; msg5=HPb (same-row overwrite, safe)
    mlp2_fused<64,true,false,false,64,false,true><<<gNP,WG,0,stream>>>(
        HPb,nullptr,B2, Wn1+4*8192,bn1+4*64,Wn2+4*4096,bn2+4*64, nullptr,HPa,
        Wm1+5*4096,bm1+5*64,Wm2+5*4096,bm2+5*64, HPb, NP, NP, fnone);
    gather_slots_k<true><<<gaNP,WG,0,stream>>>(cur_us,sl_us,CAP_US,downpool,HPb,B2,NP);

    // ---- F_n5m6: node5(hp2[downpool],B2) -> g'=HPb ; msg6=B3
    mlp2_fused<64,true,false,true,64,false,true><<<gNP,WG,0,stream>>>(
        HPa,downpool,B2, Wn1+5*8192,bn1+5*64,Wn2+5*4096,bn2+5*64, nullptr,HPb,
        Wm1+6*4096,bm1+6*64,Wm2+6*4096,bm2+6*64, B3, NP, NP, fnone);
    gather_slots_k<true><<<gaN,WG,0,stream>>>(cur_fine,sl_fine,CAP_FINE,uppool,B3,B2,N);

    // ---- F_n6m7: node6(g'[uppool],B2,+skip B1) -> h7=B0 ; msg7=B3
    mlp2_fused<64,true,true,true,64,false,true><<<gN,WG,0,stream>>>(
        HPb,uppool,B2, Wn1+6*8192,bn1+6*64,Wn2+6*4096,bn2+6*64, B1,B0,
        Wm1+7*4096,bm1+7*64,Wm2+7*4096,bm2+7*64, B3, N, N, fnone);
    gather_slots_k<false><<<gaN,WG,0,stream>>>(cur_fine,sl_fine,CAP_FINE,nullptr,B3,B2,N);

    // ---- F_n7dec: node7(h7,B2,+skip B1) -> (no out1) ; decode -> d_out
    mlp2_fused<64,true,true,false,2,false,false><<<gN,WG,0,stream>>>(
        B0,nullptr,B2, Wn1+7*8192,bn1+7*64,Wn2+7*4096,bn2+7*64, B1,nullptr,
        Wd1,bd1,Wd2,bd2, (float*)d_out, N, N, fnone);
}

// Round 9
// 950.174 us; speedup vs baseline: 1.0351x; 1.0351x over previous
//
#include <hip/hip_runtime.h>

#define WG 256

#define MLP_FMA16(ACC, A, W) do { \
    ACC[0][0]=fmaf(A.x,W.x,ACC[0][0]); ACC[0][1]=fmaf(A.x,W.y,ACC[0][1]); \
    ACC[0][2]=fmaf(A.x,W.z,ACC[0][2]); ACC[0][3]=fmaf(A.x,W.w,ACC[0][3]); \
    ACC[1][0]=fmaf(A.y,W.x,ACC[1][0]); ACC[1][1]=fmaf(A.y,W.y,ACC[1][1]); \
    ACC[1][2]=fmaf(A.y,W.z,ACC[1][2]); ACC[1][3]=fmaf(A.y,W.w,ACC[1][3]); \
    ACC[2][0]=fmaf(A.z,W.x,ACC[2][0]); ACC[2][1]=fmaf(A.z,W.y,ACC[2][1]); \
    ACC[2][2]=fmaf(A.z,W.z,ACC[2][2]); ACC[2][3]=fmaf(A.z,W.w,ACC[2][3]); \
    ACC[3][0]=fmaf(A.w,W.x,ACC[3][0]); ACC[3][1]=fmaf(A.w,W.y,ACC[3][1]); \
    ACC[3][2]=fmaf(A.w,W.z,ACC[3][2]); ACC[3][3]=fmaf(A.w,W.w,ACC[3][3]); \
} while (0)

#define PF_LOAD(P) do { \
    pf0 = *(const float4*)&(P)[pfi];        pf1 = *(const float4*)&(P)[pfi + 1024]; \
    pf2 = *(const float4*)&(P)[pfi + 2048]; pf3 = *(const float4*)&(P)[pfi + 3072]; \
} while (0)
#define PF_STORE() do { \
    *(float4*)&sW[pfi]        = pf0; *(float4*)&sW[pfi + 1024] = pf1; \
    *(float4*)&sW[pfi + 2048] = pf2; *(float4*)&sW[pfi + 3072] = pf3; \
} while (0)

// ---------------- XCD-partitioned slot fill (block role, R6 form) ----------
// R2: 8-way XCD partition keeps cur[] atomic lines XCD-local. Plain loads:
// L3 serves scan replicas 2..8. R8: dense-s co-load null -> fill is
// atomic/scatter-chain bound, bucket closed at ~130us; scattered-s kept.
__device__ __forceinline__ void fill_role(int xcd, int w,
    const int* __restrict__ s, const int* __restrict__ r,
    int* __restrict__ cur, int* __restrict__ sl,
    int cap, int E, int n, int W)
{
    const int lo = (int)(((long)n * xcd) >> 3);
    const int hi = (int)(((long)n * (xcd + 1)) >> 3);
    int chunk = (E + W - 1) / W;
    chunk = (chunk + 3) & ~3;                      // int4 alignment
    const int e0 = w * chunk;
    const int e1 = min(E, e0 + chunk);

    auto fill1 = [&](int v, int e) {
        if (v >= lo && v < hi) {
            const int sv = s[e];
            const int p = atomicAdd(&cur[v], 1);
            if (p < cap) sl[(size_t)v * cap + p] = sv;
        }
    };

    for (int e = e0 + (int)threadIdx.x * 4; e < e1; e += WG * 4) {
        if (e + 4 <= e1) {
            const int4 rv = *(const int4*)&r[e];
            fill1(rv.x, e + 0);
            fill1(rv.y, e + 1);
            fill1(rv.z, e + 2);
            fill1(rv.w, e + 3);
        } else {
            for (int j = 0; e + j < e1; ++j) fill1(r[e + j], e + j);
        }
    }
}

// fills that ride along inside an MLP dispatch (up to 2 graphs)
struct FillPair {
    const int* s0; const int* r0; int* cur0; int* sl0; int cap0, E0, n0, W0;
    const int* s1; const int* r1; int* cur1; int* sl1; int cap1, E1, n1, W1;
    int FILLB;                                     // = 8*(W0+W1); 0 = no fill
};

// =============== fused: node-MLP (+out1) then msg-MLP of next layer =========
// R1 structure + R9: weight-panel register prefetch (T14 async-stage split).
// Each staging phase was barrier -> 16KB global load -> barrier -> GEMM,
// exposing ~500cy latency 5x per block. Now the NEXT panel is loaded into
// 4 float4 regs BEFORE the current GEMM (latency hides under ~2000cy of
// FMA), and dumped regs->LDS after the barrier. +16 VGPR, no numerics change.
template<int DINA, bool HAS_B, bool HAS_SKIP, bool GATHER_A,
         int MSG_DOUT, bool PARTIAL_MSG, bool WRITE_OUT1>
__global__ __launch_bounds__(WG)
void mlp2_fused(const float* __restrict__ inA, const int* __restrict__ gidxA,
                const float* __restrict__ inB,
                const float* __restrict__ W1, const float* __restrict__ b1,
                const float* __restrict__ W2, const float* __restrict__ b2,
                const float* __restrict__ skip, float* __restrict__ out1,
                const float* __restrict__ M1, const float* __restrict__ mb1,
                const float* __restrict__ M2, const float* __restrict__ mb2,
                float* __restrict__ outM, int msgN, int n, FillPair fa)
{
    if (fa.FILLB > 0 && (int)blockIdx.x < fa.FILLB) {
        const int xcd = blockIdx.x & 7;
        const int w = blockIdx.x >> 3;
        if (w < fa.W0)
            fill_role(xcd, w, fa.s0, fa.r0, fa.cur0, fa.sl0, fa.cap0, fa.E0, fa.n0, fa.W0);
        else
            fill_role(xcd, w - fa.W0, fa.s1, fa.r1, fa.cur1, fa.sl1, fa.cap1, fa.E1, fa.n1, fa.W1);
        return;
    }
    const int bid = blockIdx.x - fa.FILLB;

    constexpr int XP = 68;                           // b128-aligned, conflict-free
    __shared__ __align__(16) float sXT[64][XP];      // X^T phases / H^T / O^T / H2^T
    __shared__ __align__(16) float sW[64 * 64];      // W1 phases / W2 / M1 / M2
    __shared__ float sb[128];
    __shared__ float sW2d[128];                      // decode W2 (64x2)
    __shared__ float sb2d[2];

    const int tid = threadIdx.x;
    const int tx = tid & 15, ty = tid >> 4;
    const int c0 = tx * 4, r0 = ty * 4;
    const int row0 = bid * 64;
    const int lrow = tid & 63;
    const int kq0 = (tid >> 6) * 4;
    const int pfi = tid * 4;

    float4 pf0, pf1, pf2, pf3;                       // weight prefetch buffer

    // ---- stage W1 phase A (DINA rows), biases
    for (int i = tid * 4; i < DINA * 64; i += WG * 4)
        *(float4*)&sW[i] = *(const float4*)&W1[i];
    if (tid < 64) sb[tid] = b1[tid];
    else if (tid < 128) sb[tid] = b2[tid - 64];

    // ---- stage X^T phase A (lane = row, conflict-free)
    {
        const int rg = min(row0 + lrow, n - 1);
        const int ra = GATHER_A ? gidxA[rg] : rg;
        const float* pA = inA + (size_t)ra * DINA;
        #pragma unroll
        for (int kq = kq0; kq < DINA; kq += 16) {
            const float4 v = *(const float4*)(pA + kq);
            sXT[kq + 0][lrow] = v.x; sXT[kq + 1][lrow] = v.y;
            sXT[kq + 2][lrow] = v.z; sXT[kq + 3][lrow] = v.w;
        }
    }
    // ---- issue prefetch of next panel (W1B if HAS_B else W2) pre-GEMM1A
    {
        const float* nxt = HAS_B ? (W1 + DINA * 64) : W2;
        PF_LOAD(nxt);
    }
    __syncthreads();

    // ---- GEMM1 phase A
    float acc[4][4] = {};
    #pragma unroll 8
    for (int k = 0; k < DINA; ++k) {
        const float4 a = *(const float4*)&sXT[k][r0];
        const float4 w = *(const float4*)&sW[k * 64 + c0];
        MLP_FMA16(acc, a, w);
    }

    // ---- GEMM1 phase B: inB against W1 rows DINA..DINA+63
    if constexpr (HAS_B) {
        __syncthreads();
        PF_STORE();                                  // W1B regs -> LDS
        {
            const int rg = min(row0 + lrow, n - 1);
            const float* pB = inB + (size_t)rg * 64;
            #pragma unroll
            for (int kq = kq0; kq < 64; kq += 16) {
                const float4 v = *(const float4*)(pB + kq);
                sXT[kq + 0][lrow] = v.x; sXT[kq + 1][lrow] = v.y;
                sXT[kq + 2][lrow] = v.z; sXT[kq + 3][lrow] = v.w;
            }
        }
        PF_LOAD(W2);                                 // prefetch W2 during GEMM1B
        __syncthreads();
        #pragma unroll 8
        for (int k = 0; k < 64; ++k) {
            const float4 a = *(const float4*)&sXT[k][r0];
            const float4 w = *(const float4*)&sW[k * 64 + c0];
            MLP_FMA16(acc, a, w);
        }
    }
    __syncthreads();

    // ---- W2 regs -> LDS; write H^T
    PF_STORE();
    #pragma unroll
    for (int j = 0; j < 4; ++j) {
        const float bj = sb[c0 + j];
        *(float4*)&sXT[c0 + j][r0] = make_float4(
            fmaxf(acc[0][j] + bj, 0.f), fmaxf(acc[1][j] + bj, 0.f),
            fmaxf(acc[2][j] + bj, 0.f), fmaxf(acc[3][j] + bj, 0.f));
    }
    if constexpr (MSG_DOUT > 0) PF_LOAD(M1);         // prefetch M1 during GEMM2
    __syncthreads();

    // ---- GEMM2
    float acc2[4][4] = {};
    #pragma unroll 8
    for (int k = 0; k < 64; ++k) {
        const float4 a = *(const float4*)&sXT[k][r0];
        const float4 w = *(const float4*)&sW[k * 64 + c0];
        MLP_FMA16(acc2, a, w);
    }

    // ---- O = acc2 + b2 (+skip); write out1
    float ofull[4][4];
    #pragma unroll
    for (int i = 0; i < 4; ++i) {
        const int row = row0 + r0 + i;
        float4 s = make_float4(0.f, 0.f, 0.f, 0.f);
        if (HAS_SKIP && row < n) s = *(const float4*)&skip[(size_t)row * 64 + c0];
        ofull[i][0] = acc2[i][0] + sb[64 + c0 + 0] + s.x;
        ofull[i][1] = acc2[i][1] + sb[64 + c0 + 1] + s.y;
        ofull[i][2] = acc2[i][2] + sb[64 + c0 + 2] + s.z;
        ofull[i][3] = acc2[i][3] + sb[64 + c0 + 3] + s.w;
        if (WRITE_OUT1 && row < n)
            *(float4*)&out1[(size_t)row * 64 + c0] =
                make_float4(ofull[i][0], ofull[i][1], ofull[i][2], ofull[i][3]);
    }

    // ================= msg tail =================
    if constexpr (MSG_DOUT > 0) {
        if (!PARTIAL_MSG || row0 < msgN) {   // block-uniform
            __syncthreads();
            PF_STORE();                              // M1 regs -> LDS
            if constexpr (MSG_DOUT == 64) {
                if (tid < 64) sb[tid] = mb1[tid];
                else if (tid < 128) sb[tid] = mb2[tid - 64];
            } else {
                if (tid < 64) sb[tid] = mb1[tid];
                else if (tid < 192) sW2d[tid - 64] = M2[tid - 64];
                else if (tid < 194) sb2d[tid - 192] = mb2[tid - 192];
            }
            #pragma unroll
            for (int j = 0; j < 4; ++j)
                *(float4*)&sXT[c0 + j][r0] =
                    make_float4(ofull[0][j], ofull[1][j], ofull[2][j], ofull[3][j]);
            if constexpr (MSG_DOUT == 64) PF_LOAD(M2);   // prefetch M2 during GEMM3
            __syncthreads();

            // GEMM3: H2 = relu(O @ M1 + mb1)
            float acc3[4][4] = {};
            #pragma unroll 8
            for (int k = 0; k < 64; ++k) {
                const float4 a = *(const float4*)&sXT[k][r0];
                const float4 w = *(const float4*)&sW[k * 64 + c0];
                MLP_FMA16(acc3, a, w);
            }
            __syncthreads();
            if constexpr (MSG_DOUT == 64) PF_STORE();    // M2 regs -> LDS
            #pragma unroll
            for (int j = 0; j < 4; ++j) {
                const float bj = sb[c0 + j];
                *(float4*)&sXT[c0 + j][r0] = make_float4(
                    fmaxf(acc3[0][j] + bj, 0.f), fmaxf(acc3[1][j] + bj, 0.f),
                    fmaxf(acc3[2][j] + bj, 0.f), fmaxf(acc3[3][j] + bj, 0.f));
            }
            __syncthreads();

            if constexpr (MSG_DOUT == 64) {
                float accM[4][4] = {};
                #pragma unroll 8
                for (int k = 0; k < 64; ++k) {
                    const float4 a = *(const float4*)&sXT[k][r0];
                    const float4 w = *(const float4*)&sW[k * 64 + c0];
                    MLP_FMA16(accM, a, w);
                }
                #pragma unroll
                for (int i = 0; i < 4; ++i) {
                    const int row = row0 + r0 + i;
                    if (row < msgN)
                        *(float4*)&outM[(size_t)row * 64 + c0] =
                            make_float4(accM[i][0] + sb[64 + c0 + 0],
                                        accM[i][1] + sb[64 + c0 + 1],
                                        accM[i][2] + sb[64 + c0 + 2],
                                        accM[i][3] + sb[64 + c0 + 3]);
                }
            } else {
                // decode: 128 threads: (row,col)=(tid>>1, tid&1)
                if (tid < 128) {
                    const int lr = tid >> 1, col = tid & 1;
                    float o0 = sb2d[col], o1 = 0.0f;
                    #pragma unroll 8
                    for (int k = 0; k < 64; k += 2) {
                        o0 = fmaf(sXT[k][lr],     sW2d[k * 2 + col],       o0);
                        o1 = fmaf(sXT[k + 1][lr], sW2d[(k + 1) * 2 + col], o1);
                    }
                    const int row = row0 + lr;
                    if (row < msgN) outM[(size_t)row * 2 + col] = o0 + o1;
                }
            }
        }
    }
}

// plain node-only MLP, R1 structure + R9 weight prefetch
template<int DINA, bool HAS_B, bool HAS_SKIP, bool GATHER_A>
__global__ __launch_bounds__(WG)
void mlp2_rt(const float* __restrict__ inA, const int* __restrict__ gidxA,
             const float* __restrict__ inB,
             const float* __restrict__ W1, const float* __restrict__ b1,
             const float* __restrict__ W2, const float* __restrict__ b2,
             const float* __restrict__ skip,
             float* __restrict__ out, int n)
{
    constexpr int XP = 68;
    __shared__ __align__(16) float sXT[64][XP];
    __shared__ __align__(16) float sW[64 * 64];
    __shared__ float sb[128];

    const int tid = threadIdx.x;
    const int tx = tid & 15, ty = tid >> 4;
    const int c0 = tx * 4, r0 = ty * 4;
    const int row0 = blockIdx.x * 64;
    const int lrow = tid & 63;
    const int kq0 = (tid >> 6) * 4;
    const int pfi = tid * 4;

    float4 pf0, pf1, pf2, pf3;

    for (int i = tid * 4; i < DINA * 64; i += WG * 4)
        *(float4*)&sW[i] = *(const float4*)&W1[i];
    if (tid < 64) sb[tid] = b1[tid];
    else if (tid < 128) sb[tid] = b2[tid - 64];

    {
        const int rg = min(row0 + lrow, n - 1);
        const int ra = GATHER_A ? gidxA[rg] : rg;
        const float* pA = inA + (size_t)ra * DINA;
        #pragma unroll
        for (int kq = kq0; kq < DINA; kq += 16) {
            const float4 v = *(const float4*)(pA + kq);
            sXT[kq + 0][lrow] = v.x; sXT[kq + 1][lrow] = v.y;
            sXT[kq + 2][lrow] = v.z; sXT[kq + 3][lrow] = v.w;
        }
    }
    {
        const float* nxt = HAS_B ? (W1 + DINA * 64) : W2;
        PF_LOAD(nxt);
    }
    __syncthreads();

    float acc[4][4] = {};
    #pragma unroll 8
    for (int k = 0; k < DINA; ++k) {
        const float4 a = *(const float4*)&sXT[k][r0];
        const float4 w = *(const float4*)&sW[k * 64 + c0];
        MLP_FMA16(acc, a, w);
    }
    if constexpr (HAS_B) {
        __syncthreads();
        PF_STORE();
        {
            const int rg = min(row0 + lrow, n - 1);
            const float* pB = inB + (size_t)rg * 64;
            #pragma unroll
            for (int kq = kq0; kq < 64; kq += 16) {
                const float4 v = *(const float4*)(pB + kq);
                sXT[kq + 0][lrow] = v.x; sXT[kq + 1][lrow] = v.y;
                sXT[kq + 2][lrow] = v.z; sXT[kq + 3][lrow] = v.w;
            }
        }
        PF_LOAD(W2);
        __syncthreads();
        #pragma unroll 8
        for (int k = 0; k < 64; ++k) {
            const float4 a = *(const float4*)&sXT[k][r0];
            const float4 w = *(const float4*)&sW[k * 64 + c0];
            MLP_FMA16(acc, a, w);
        }
    }
    __syncthreads();

    PF_STORE();
    #pragma unroll
    for (int j = 0; j < 4; ++j) {
        const float bj = sb[c0 + j];
        *(float4*)&sXT[c0 + j][r0] = make_float4(
            fmaxf(acc[0][j] + bj, 0.f), fmaxf(acc[1][j] + bj, 0.f),
            fmaxf(acc[2][j] + bj, 0.f), fmaxf(acc[3][j] + bj, 0.f));
    }
    __syncthreads();

    float acc2[4][4] = {};
    #pragma unroll 8
    for (int k = 0; k < 64; ++k) {
        const float4 a = *(const float4*)&sXT[k][r0];
        const float4 w = *(const float4*)&sW[k * 64 + c0];
        MLP_FMA16(acc2, a, w);
    }
    #pragma unroll
    for (int i = 0; i < 4; ++i) {
        const int row = row0 + r0 + i;
        if (row < n) {
            float4 o = make_float4(acc2[i][0] + sb[64 + c0 + 0],
                                   acc2[i][1] + sb[64 + c0 + 1],
                                   acc2[i][2] + sb[64 + c0 + 2],
                                   acc2[i][3] + sb[64 + c0 + 3]);
            if (HAS_SKIP) {
                const float4 s = *(const float4*)&skip[(size_t)row * 64 + c0];
                o.x += s.x; o.y += s.y; o.z += s.z; o.w += s.w;
            }
            *(float4*)&out[(size_t)row * 64 + c0] = o;
        }
    }
}

// ===== dispatch 1: fine-graph fill UNION encode+msg0 MLP (R6 verbatim) ======
__global__ __launch_bounds__(WG)
void fill_enc_k(const int* __restrict__ s0, const int* __restrict__ r0v,
                int* cu0, int* sl0, int cap0, int E0, int n0, int W0, int FILLB,
                const float* __restrict__ x,
                const float* __restrict__ We1, const float* __restrict__ be1,
                const float* __restrict__ We2, const float* __restrict__ be2,
                float* __restrict__ h0,
                const float* __restrict__ M1, const float* __restrict__ mb1,
                const float* __restrict__ M2, const float* __restrict__ mb2,
                float* __restrict__ msg0, int N)
{
    constexpr int XP = 68;
    __shared__ __align__(16) float sXT[64][XP];
    __shared__ float sb[128];

    if ((int)blockIdx.x < FILLB) {
        fill_role(blockIdx.x & 7, blockIdx.x >> 3, s0, r0v, cu0, sl0, cap0, E0, n0, W0);
        return;
    }

    // ---------------- encode role: h0 = MLP2(x); msg0 = MLP2(h0) ----------------
    const int bid = blockIdx.x - FILLB;
    const int tid = threadIdx.x;
    const int tx = tid & 15, ty = tid >> 4;
    const int c0 = tx * 4, r0 = ty * 4;
    const int row0 = bid * 64;
    const int lrow = tid & 63;
    const int kq0 = (tid >> 6) * 4;

    if (tid < 64) sb[tid] = be1[tid];
    else if (tid < 128) sb[tid] = be2[tid - 64];

    {
        const int rg = min(row0 + lrow, N - 1);
        const float* pA = x + (size_t)rg * 16;
        const float4 v = *(const float4*)(pA + kq0);
        sXT[kq0 + 0][lrow] = v.x; sXT[kq0 + 1][lrow] = v.y;
        sXT[kq0 + 2][lrow] = v.z; sXT[kq0 + 3][lrow] = v.w;
    }
    __syncthreads();

    float acc[4][4] = {};
    #pragma unroll
    for (int k = 0; k < 16; ++k) {
        const float4 a = *(const float4*)&sXT[k][r0];
        const float4 w = *(const float4*)&We1[k * 64 + c0];
        MLP_FMA16(acc, a, w);
    }
    __syncthreads();
    #pragma unroll
    for (int j = 0; j < 4; ++j) {
        const float bj = sb[c0 + j];
        *(float4*)&sXT[c0 + j][r0] = make_float4(
            fmaxf(acc[0][j] + bj, 0.f), fmaxf(acc[1][j] + bj, 0.f),
            fmaxf(acc[2][j] + bj, 0.f), fmaxf(acc[3][j] + bj, 0.f));
    }
    __syncthreads();

    float acc2[4][4] = {};
    #pragma unroll 8
    for (int k = 0; k < 64; ++k) {
        const float4 a = *(const float4*)&sXT[k][r0];
        const float4 w = *(const float4*)&We2[k * 64 + c0];
        MLP_FMA16(acc2, a, w);
    }
    float ofull[4][4];
    #pragma unroll
    for (int i = 0; i < 4; ++i) {
        const int row = row0 + r0 + i;
        ofull[i][0] = acc2[i][0] + sb[64 + c0 + 0];
        ofull[i][1] = acc2[i][1] + sb[64 + c0 + 1];
        ofull[i][2] = acc2[i][2] + sb[64 + c0 + 2];
        ofull[i][3] = acc2[i][3] + sb[64 + c0 + 3];
        if (row < N)
            *(float4*)&h0[(size_t)row * 64 + c0] =
                make_float4(ofull[i][0], ofull[i][1], ofull[i][2], ofull[i][3]);
    }

    __syncthreads();
    if (tid < 64) sb[tid] = mb1[tid];
    else if (tid < 128) sb[tid] = mb2[tid - 64];
    #pragma unroll
    for (int j = 0; j < 4; ++j)
        *(float4*)&sXT[c0 + j][r0] =
            make_float4(ofull[0][j], ofull[1][j], ofull[2][j], ofull[3][j]);
    __syncthreads();

    float acc3[4][4] = {};
    #pragma unroll 8
    for (int k = 0; k < 64; ++k) {
        const float4 a = *(const float4*)&sXT[k][r0];
        const float4 w = *(const float4*)&M1[k * 64 + c0];
        MLP_FMA16(acc3, a, w);
    }
    __syncthreads();
    #pragma unroll
    for (int j = 0; j < 4; ++j) {
        const float bj = sb[c0 + j];
        *(float4*)&sXT[c0 + j][r0] = make_float4(
            fmaxf(acc3[0][j] + bj, 0.f), fmaxf(acc3[1][j] + bj, 0.f),
            fmaxf(acc3[2][j] + bj, 0.f), fmaxf(acc3[3][j] + bj, 0.f));
    }
    __syncthreads();

    float accM[4][4] = {};
    #pragma unroll 8
    for (int k = 0; k < 64; ++k) {
        const float4 a = *(const float4*)&sXT[k][r0];
        const float4 w = *(const float4*)&M2[k * 64 + c0];
        MLP_FMA16(accM, a, w);
    }
    #pragma unroll
    for (int i = 0; i < 4; ++i) {
        const int row = row0 + r0 + i;
        if (row < N)
            *(float4*)&msg0[(size_t)row * 64 + c0] =
                make_float4(accM[i][0] + sb[64 + c0 + 0],
                            accM[i][1] + sb[64 + c0 + 1],
                            accM[i][2] + sb[64 + c0 + 2],
                            accM[i][3] + sb[64 + c0 + 3]);
    }
}

// ---------------- slot gather-sum: float4 rows, 4 rows/wave-instr (R6) -----
template<bool REMAP>
__global__ __launch_bounds__(WG)
void gather_slots_k(const int* __restrict__ deg, const int* __restrict__ slots,
                    int cap, const int* __restrict__ remap,
                    const float* __restrict__ tab, float* __restrict__ aggr, int n)
{
    const int node = blockIdx.x * (WG / 64) + (threadIdx.x >> 6);
    const int lane = threadIdx.x & 63;
    if (node >= n) return;
    const int d = min(deg[node], cap);
    const int* sl = slots + (size_t)node * cap;

    int myidx = 0;
    if (lane < d) {
        myidx = sl[lane];
        if (REMAP) myidx = remap[myidx];
    }

    const int g  = lane >> 4;          // row-group 0..3
    const int c4 = (lane & 15) * 4;    // column quad

    float4 a0 = make_float4(0.f, 0.f, 0.f, 0.f);
    float4 a1 = make_float4(0.f, 0.f, 0.f, 0.f);
    float4 a2 = make_float4(0.f, 0.f, 0.f, 0.f);
    float4 a3 = make_float4(0.f, 0.f, 0.f, 0.f);

    int j = 0;
    for (; j + 16 <= d; j += 16) {
        const int t0 = __shfl(myidx, j + g);
        const int t1 = __shfl(myidx, j + 4 + g);
        const int t2 = __shfl(myidx, j + 8 + g);
        const int t3 = __shfl(myidx, j + 12 + g);
        const float4 v0 = *(const float4*)&tab[(size_t)t0 * 64 + c4];
        const float4 v1 = *(const float4*)&tab[(size_t)t1 * 64 + c4];
        const float4 v2 = *(const float4*)&tab[(size_t)t2 * 64 + c4];
        const float4 v3 = *(const float4*)&tab[(size_t)t3 * 64 + c4];
        a0.x += v0.x; a0.y += v0.y; a0.z += v0.z; a0.w += v0.w;
        a1.x += v1.x; a1.y += v1.y; a1.z += v1.z; a1.w += v1.w;
        a2.x += v2.x; a2.y += v2.y; a2.z += v2.z; a2.w += v2.w;
        a3.x += v3.x; a3.y += v3.y; a3.z += v3.z; a3.w += v3.w;
    }
    for (; j < d; j += 4) {
        const int jj = j + g;
        const int t = __shfl(myidx, jj < 63 ? jj : 0);   // uniform shfl
        if (jj < d) {
            const float4 v = *(const float4*)&tab[(size_t)t * 64 + c4];
            a0.x += v.x; a0.y += v.y; a0.z += v.z; a0.w += v.w;
        }
    }

    // combine accumulators, then reduce across the 4 row-groups
    a0.x += a1.x + a2.x + a3.x;
    a0.y += a1.y + a2.y + a3.y;
    a0.z += a1.z + a2.z + a3.z;
    a0.w += a1.w + a2.w + a3.w;

    a0.x += __shfl_xor(a0.x, 16); a0.y += __shfl_xor(a0.y, 16);
    a0.z += __shfl_xor(a0.z, 16); a0.w += __shfl_xor(a0.w, 16);
    a0.x += __shfl_xor(a0.x, 32); a0.y += __shfl_xor(a0.y, 32);
    a0.z += __shfl_xor(a0.z, 32); a0.w += __shfl_xor(a0.w, 32);

    if (lane < 16)
        *(float4*)&aggr[(size_t)node * 64 + c4] = a0;
}

extern "C" void kernel_launch(void* const* d_in, const int* in_sizes, int n_in,
                              void* d_out, int out_size, void* d_ws, size_t ws_size,
                              hipStream_t stream)
{
    const float* x    = (const float*)d_in[0];
    const float* We1  = (const float*)d_in[1];
    const float* be1  = (const float*)d_in[2];
    const float* We2  = (const float*)d_in[3];
    const float* be2  = (const float*)d_in[4];
    const float* Wm1  = (const float*)d_in[5];
    const float* bm1  = (const float*)d_in[6];
    const float* Wm2  = (const float*)d_in[7];
    const float* bm2  = (const float*)d_in[8];
    const float* Wn1  = (const float*)d_in[9];
    const float* bn1  = (const float*)d_in[10];
    const float* Wn2  = (const float*)d_in[11];
    const float* bn2  = (const float*)d_in[12];
    const float* Wd1  = (const float*)d_in[13];
    const float* bd1  = (const float*)d_in[14];
    const float* Wd2  = (const float*)d_in[15];
    const float* bd2  = (const float*)d_in[16];
    const int* s_fine = (const int*)d_in[17];
    const int* r_fine = (const int*)d_in[18];
    const int* s_ds   = (const int*)d_in[19];
    const int* r_ds   = (const int*)d_in[20];
    const int* s_p    = (const int*)d_in[21];
    const int* r_p    = (const int*)d_in[22];
    const int* s_us   = (const int*)d_in[23];
    const int* r_us   = (const int*)d_in[24];
    const int* uppool   = (const int*)d_in[25];
    const int* downpool = (const int*)d_in[26];

    const int N   = in_sizes[0] / 16;
    const int E   = in_sizes[17];
    const int EDS = in_sizes[19];
    const int EP  = in_sizes[21];
    const int EUS = in_sizes[23];
    const int NP  = in_sizes[26];

    const int CAP_FINE = 48, CAP_DS = 32, CAP_PP = 48, CAP_US = 32;

    // ---- workspace ----
    float* B0  = (float*)d_ws;
    float* B1  = B0 + (size_t)N * 64;
    float* B2  = B1 + (size_t)N * 64;
    float* B3  = B2 + (size_t)N * 64;
    float* HPa = B3 + (size_t)N * 64;
    float* HPb = HPa + (size_t)NP * 64;
    int* ip = (int*)(HPb + (size_t)NP * 64);
    auto alloc_i = [&](size_t n) { int* p = ip; ip += n; return p; };
    int* cur_fine = alloc_i(N);
    int* cur_ds   = alloc_i(N);
    int* cur_pp   = alloc_i(NP);
    int* cur_us   = alloc_i(NP);
    int* sl_fine  = alloc_i((size_t)N * CAP_FINE);
    int* sl_ds    = alloc_i((size_t)N * CAP_DS);
    int* sl_pp    = alloc_i((size_t)NP * CAP_PP);
    int* sl_us    = alloc_i((size_t)NP * CAP_US);

    const int gN  = (N + 63) / 64;
    const int gNP = (NP + 63) / 64;
    const int gaN  = (N + 3) / 4;
    const int gaNP = (NP + 3) / 4;

    const FillPair fnone = {};

    // ---- fine fill + encode in one dispatch (ds/pp/us fills deferred)
    hipMemsetAsync(cur_fine, 0, (size_t)(2 * N + 2 * NP) * sizeof(int), stream);
    {
        const int W_FINE = 256;
        const int FILLB = 8 * W_FINE;   // 2048
        fill_enc_k<<<FILLB + gN, WG, 0, stream>>>(
            s_fine, r_fine, cur_fine, sl_fine, CAP_FINE, E, N, W_FINE, FILLB,
            x, We1, be1, We2, be2, B0,
            Wm1 + 0*4096, bm1 + 0*64, Wm2 + 0*4096, bm2 + 0*64, B1, N);
    }
    gather_slots_k<false><<<gaN,WG,0,stream>>>(cur_fine,sl_fine,CAP_FINE,nullptr,B1,B2,N);

    // ---- F_n0m1: node0(h0,B2) -> h1=B3 ; msg1=B0  [+ ds fill riding along]
    {
        const int W_DS = 128;
        FillPair fds = { s_ds, r_ds, cur_ds, sl_ds, CAP_DS, EDS, N, W_DS,
                         nullptr, nullptr, nullptr, nullptr, 0, 0, 0, 0,
                         8 * W_DS };
        mlp2_fused<64,true,false,false,64,false,true><<<8*128 + gN,WG,0,stream>>>(
            B0,nullptr,B2, Wn1+0*8192,bn1+0*64,Wn2+0*4096,bn2+0*64, nullptr,B3,
            Wm1+1*4096,bm1+1*64,Wm2+1*4096,bm2+1*64, B0, N, N, fds);
    }
    gather_slots_k<false><<<gaN,WG,0,stream>>>(cur_fine,sl_fine,CAP_FINE,nullptr,B0,B2,N);

    // ---- F_n1m2: node1(h1,B2) -> h2=B1 (skip) ; msg2=B0 rows<NP  [+ pp & us fills]
    {
        const int W_PP = 64, W_US = 32;
        FillPair fpu = { s_p,  r_p,  cur_pp, sl_pp, CAP_PP, EP,  NP, W_PP,
                         s_us, r_us, cur_us, sl_us, CAP_US, EUS, NP, W_US,
                         8 * (W_PP + W_US) };
        mlp2_fused<64,true,false,false,64,true,true><<<8*(64+32) + gN,WG,0,stream>>>(
            B3,nullptr,B2, Wn1+1*8192,bn1+1*64,Wn2+1*4096,bn2+1*64, nullptr,B1,
            Wm1+2*4096,bm1+2*64,Wm2+2*4096,bm2+2*64, B0, NP, N, fpu);
    }
    gather_slots_k<true><<<gaN,WG,0,stream>>>(cur_ds,sl_ds,CAP_DS,uppool,B0,B2,N);

    // ---- N2: node2 (h2[uppool], B2) -> g=B3
    mlp2_rt<64,true,false,true><<<gN,WG,0,stream>>>(
        B1,uppool,B2, Wn1+2*8192,bn1+2*64,Wn2+2*4096,bn2+2*64, nullptr,B3,N);

    // ---- M3: msg3 over g[downpool] -> HPa
    mlp2_rt<64,false,false,true><<<gNP,WG,0,stream>>>(
        B3,downpool,nullptr, Wm1+3*4096,bm1+3*64,Wm2+3*4096,bm2+3*64, nullptr,HPa,NP);
    gather_slots_k<false><<<gaNP,WG,0,stream>>>(cur_pp,sl_pp,CAP_PP,nullptr,HPa,B2,NP);

    // ---- F_n3m4: node3(g[downpool],B2) -> hp1=HPb ; msg4=HPa
    mlp2_fused<64,true,false,true,64,false,true><<<gNP,WG,0,stream>>>(
        B3,downpool,B2, Wn1+3*8192,bn1+3*64,Wn2+3*4096,bn2+3*64, nullptr,HPb,
        Wm1+4*4096,bm1+4*64,Wm2+4*4096,bm2+4*64, HPa, NP, NP, fnone);
    gather_slots_k<false><<<gaNP,WG,0,stream>>>(cur_pp,sl_pp,CAP_PP,nullptr,HPa,B2,NP);

    // ---- F_n4m5: node4(hp1,B2) -> hp2=HPa ; msg5=HPb (same-row overwrite, safe)
    mlp2_fused<64,true,false,false,64,false,true><<<gNP,WG,0,stream>>>(
        HPb,nullptr,B2, Wn1+4*8192,bn1+4*64,Wn2+4*4096,bn2+4*64, nullptr,HPa,
        Wm1+5*4096,bm1+5*64,Wm2+5*4096,bm2+5*64, HPb, NP, NP, fnone);
    gather_slots_k<true><<<gaNP,WG,0,stream>>>(cur_us,sl_us,CAP_US,downpool,HPb,B2,NP);

    // ---- F_n5m6: node5(hp2[downpool],B2) -> g'=HPb ; msg6=B3
    mlp2_fused<64,true,false,true,64,false,true><<<gNP,WG,0,stream>>>(
        HPa,downpool,B2, Wn1+5*8192,bn1+5*64,Wn2+5*4096,bn2+5*64, nullptr,HPb,
        Wm1+6*4096,bm1+6*64,Wm2+6*4096,bm2+6*64, B3, NP, NP, fnone);
    gather_slots_k<true><<<gaN,WG,0,stream>>>(cur_fine,sl_fine,CAP_FINE,uppool,B3,B2,N);

    // ---- F_n6m7: node6(g'[uppool],B2,+skip B1) -> h7=B0 ; msg7=B3
    mlp2_fused<64,true,true,true,64,false,true><<<gN,WG,0,stream>>>(
        HPb,uppool,B2, Wn1+6*8192,bn1+6*64,Wn2+6*4096,bn2+6*64, B1,B0,
        Wm1+7*4096,bm1+7*64,Wm2+7*4096,bm2+7*64, B3, N, N, fnone);
    gather_slots_k<false><<<gaN,WG,0,stream>>>(cur_fine,sl_fine,CAP_FINE,nullptr,B3,B2,N);

    // ---- F_n7dec: node7(h7,B2,+skip B1) -> (no out1) ; decode -> d_out
    mlp2_fused<64,true,true,false,2,false,false><<<gN,WG,0,stream>>>(
        B0,nullptr,B2, Wn1+7*8192,bn1+7*64,Wn2+7*4096,bn2+7*64, B1,nullptr,
        Wd1,bd1,Wd2,bd2, (float*)d_out, N, N, fnone);
}